// Round 5
// baseline (5988.137 us; speedup 1.0000x reference)
//
#include <hip/hip_runtime.h>

#define HID 32
#define NFEAT 64

// ---------------------------------------------------------------------------
// Graph preprocessing (loop-invariant, rebuilt every launch)
// ---------------------------------------------------------------------------

__global__ void hist_kernel(const int* __restrict__ dstP, const int* __restrict__ dstN,
                            int* __restrict__ cntP, int* __restrict__ cntN, int E) {
    int stride = gridDim.x * blockDim.x;
    for (int idx = blockIdx.x * blockDim.x + threadIdx.x; idx < 2 * E; idx += stride) {
        if (idx < E) atomicAdd(&cntP[dstP[idx]], 1);
        else         atomicAdd(&cntN[dstN[idx - E]], 1);
    }
}

__global__ void deg_kernel(const int* __restrict__ cntP, const int* __restrict__ cntN,
                           float* __restrict__ dinvP, float* __restrict__ invdegP,
                           float* __restrict__ dinvN, float* __restrict__ invdegN, int n) {
    int i = blockIdx.x * blockDim.x + threadIdx.x;
    if (i >= n) return;
    float dp = (float)cntP[i] + 1.0f;
    dinvP[i] = rsqrtf(dp);
    invdegP[i] = 1.0f / dp;
    float dn = (float)cntN[i] + 1.0f;
    dinvN[i] = rsqrtf(dn);
    invdegN[i] = 1.0f / dn;
}

// Exclusive scan of cnt -> row_ptr (one block per graph, sequential chunks).
__global__ void scan_kernel(const int* __restrict__ cntP, const int* __restrict__ cntN,
                            int* __restrict__ rpP, int* __restrict__ rpN, int n) {
    const int* cnt = blockIdx.x ? cntN : cntP;
    int* rp = blockIdx.x ? rpN : rpP;
    __shared__ int buf[1024];
    __shared__ int carry;
    int tid = threadIdx.x;
    if (tid == 0) carry = 0;
    __syncthreads();
    for (int base = 0; base < n; base += 1024) {
        int i = base + tid;
        int v = (i < n) ? cnt[i] : 0;
        buf[tid] = v;
        __syncthreads();
        for (int off = 1; off < 1024; off <<= 1) {
            int t = (tid >= off) ? buf[tid - off] : 0;
            __syncthreads();
            buf[tid] += t;
            __syncthreads();
        }
        int c = carry;
        if (i < n) rp[i] = c + buf[tid] - v;   // exclusive
        __syncthreads();
        if (tid == 1023) carry = c + buf[1023];
        __syncthreads();
    }
    if (tid == 0) rp[n] = carry;
}

__global__ void fill_kernel(const int* __restrict__ srcP, const int* __restrict__ dstP,
                            const int* __restrict__ srcN, const int* __restrict__ dstN,
                            const float* __restrict__ dinvP, const float* __restrict__ dinvN,
                            int* __restrict__ curP, int* __restrict__ curN,
                            int* __restrict__ colP, float* __restrict__ cofP,
                            int* __restrict__ colN, float* __restrict__ cofN, int E) {
    int stride = gridDim.x * blockDim.x;
    for (int idx = blockIdx.x * blockDim.x + threadIdx.x; idx < 2 * E; idx += stride) {
        if (idx < E) {
            int s = srcP[idx], d = dstP[idx];
            int p = atomicAdd(&curP[d], 1);
            colP[p] = s;
            cofP[p] = dinvP[s] * dinvP[d];
        } else {
            int e = idx - E;
            int s = srcN[e], d = dstN[e];
            int p = atomicAdd(&curN[d], 1);
            colN[p] = s;
            cofN[p] = dinvN[s] * dinvN[d];
        }
    }
}

// ---------------------------------------------------------------------------
// Combined weights: Wpp = Wp @ Psi_top, Wnn = Wn @ Psi_bot,
// cbias = bp @ Psi_top + bn @ Psi_bot.   (one 1024-thread block, runs once)
// ---------------------------------------------------------------------------

__global__ void wcomb_kernel(const float* __restrict__ wp, const float* __restrict__ bp,
                             const float* __restrict__ wn, const float* __restrict__ bn,
                             const float* __restrict__ psi,
                             float* __restrict__ wpp, float* __restrict__ wnn,
                             float* __restrict__ cb) {
    int tid = threadIdx.x;
    int j = tid >> 5, f = tid & 31;
    float sp = 0.f, sn = 0.f;
    #pragma unroll
    for (int k = 0; k < HID; ++k) {
        sp += wp[j * HID + k] * psi[k * HID + f];
        sn += wn[j * HID + k] * psi[(HID + k) * HID + f];
    }
    wpp[j * HID + f] = sp;
    wnn[j * HID + f] = sn;
    if (j == 0) {
        float s = 0.f;
        #pragma unroll
        for (int k = 0; k < HID; ++k)
            s += bp[k] * psi[k * HID + f] + bn[k] * psi[(HID + k) * HID + f];
        cb[f] = s;
    }
}

// ---------------------------------------------------------------------------
// Encoder: h0 = LN(x @ w_enc + b_enc; g_feat,b_feat); hn = LN(h0; g_ode,b_ode)
// ---------------------------------------------------------------------------

__global__ __launch_bounds__(256) void encoder_kernel(
        const float* __restrict__ x, const float* __restrict__ w_enc,
        const float* __restrict__ b_enc, const float* __restrict__ g_feat,
        const float* __restrict__ b_feat, const float* __restrict__ g_ode,
        const float* __restrict__ b_ode,
        float* __restrict__ h, float* __restrict__ hn, int n) {
    __shared__ float sW[NFEAT][HID];
    __shared__ float sBe[HID], sGf[HID], sBf[HID], sGo[HID], sBo[HID];
    for (int k = threadIdx.x; k < NFEAT * HID; k += blockDim.x)
        sW[k >> 5][k & 31] = w_enc[k];
    if (threadIdx.x < HID) {
        sBe[threadIdx.x] = b_enc[threadIdx.x];
        sGf[threadIdx.x] = g_feat[threadIdx.x];
        sBf[threadIdx.x] = b_feat[threadIdx.x];
        sGo[threadIdx.x] = g_ode[threadIdx.x];
        sBo[threadIdx.x] = b_ode[threadIdx.x];
    }
    __syncthreads();
    int i = blockIdx.x * blockDim.x + threadIdx.x;
    if (i >= n) return;

    float acc[HID];
    #pragma unroll
    for (int f = 0; f < HID; ++f) acc[f] = sBe[f];
    const float4* xr = reinterpret_cast<const float4*>(x + (size_t)i * NFEAT);
    #pragma unroll 2
    for (int q = 0; q < NFEAT / 4; ++q) {
        float4 a = xr[q];
        #pragma unroll
        for (int r = 0; r < 4; ++r) {
            float av = (r == 0) ? a.x : (r == 1) ? a.y : (r == 2) ? a.z : a.w;
            const float4* wr = reinterpret_cast<const float4*>(sW[4 * q + r]);
            #pragma unroll
            for (int f4 = 0; f4 < HID / 4; ++f4) {
                float4 w = wr[f4];
                acc[4 * f4 + 0] += av * w.x;
                acc[4 * f4 + 1] += av * w.y;
                acc[4 * f4 + 2] += av * w.z;
                acc[4 * f4 + 3] += av * w.w;
            }
        }
    }
    // LN (feat)
    float m = 0.f;
    #pragma unroll
    for (int f = 0; f < HID; ++f) m += acc[f];
    m *= (1.0f / HID);
    float var = 0.f;
    #pragma unroll
    for (int f = 0; f < HID; ++f) { float d = acc[f] - m; var += d * d; }
    var *= (1.0f / HID);
    float rs = rsqrtf(var + 1e-5f);
    #pragma unroll
    for (int f = 0; f < HID; ++f) acc[f] = (acc[f] - m) * rs * sGf[f] + sBf[f];

    float4* hw = reinterpret_cast<float4*>(h + (size_t)i * HID);
    #pragma unroll
    for (int q = 0; q < HID / 4; ++q)
        hw[q] = make_float4(acc[4*q], acc[4*q+1], acc[4*q+2], acc[4*q+3]);

    // LN (ode) -> hn
    m = 0.f;
    #pragma unroll
    for (int f = 0; f < HID; ++f) m += acc[f];
    m *= (1.0f / HID);
    var = 0.f;
    #pragma unroll
    for (int f = 0; f < HID; ++f) { float d = acc[f] - m; var += d * d; }
    var *= (1.0f / HID);
    rs = rsqrtf(var + 1e-5f);
    float4* hnw = reinterpret_cast<float4*>(hn + (size_t)i * HID);
    #pragma unroll
    for (int q = 0; q < HID / 4; ++q)
        hnw[q] = make_float4((acc[4*q+0] - m) * rs * sGo[4*q+0] + sBo[4*q+0],
                             (acc[4*q+1] - m) * rs * sGo[4*q+1] + sBo[4*q+1],
                             (acc[4*q+2] - m) * rs * sGo[4*q+2] + sBo[4*q+2],
                             (acc[4*q+3] - m) * rs * sGo[4*q+3] + sBo[4*q+3]);
}

// ---------------------------------------------------------------------------
// Fused ODE-eval kernel: one 32-lane group per node (lane f = feature f).
//   aggp/aggn via gather over hn_cur (fixed-trip unrolled chunks of 32),
//   32x32 matmuls via __shfl broadcast + LDS weights,
//   tanh/clip, RK4 stage update, LayerNorm of next state -> hn_next.
// hn is ping-ponged across evals (gathers read hn_cur, LN writes hn_next),
// so there is no read/write race between blocks.
// ---------------------------------------------------------------------------

template<int STAGE, bool LAST>
__global__ __launch_bounds__(256) void fused_kernel(
        const float* __restrict__ hn_cur, float* __restrict__ hn_next,
        const int* __restrict__ rpP, const int* __restrict__ colP,
        const float* __restrict__ cofP, const float* __restrict__ invdegP,
        const int* __restrict__ rpN, const int* __restrict__ colN,
        const float* __restrict__ cofN, const float* __restrict__ invdegN,
        const float* __restrict__ wpp, const float* __restrict__ wnn,
        const float* __restrict__ cb,
        const float* __restrict__ g_ode, const float* __restrict__ b_ode,
        const float* __restrict__ t,
        float* __restrict__ h, float* __restrict__ kacc,
        float* __restrict__ out, int n) {
    __shared__ float sWp[HID][HID];
    __shared__ float sWn[HID][HID];
    __shared__ float sCb[HID], sGo[HID], sBo[HID];
    for (int k = threadIdx.x; k < HID * HID; k += blockDim.x) {
        sWp[k >> 5][k & 31] = wpp[k];
        sWn[k >> 5][k & 31] = wnn[k];
    }
    if (threadIdx.x < HID) {
        sCb[threadIdx.x] = cb[threadIdx.x];
        sGo[threadIdx.x] = g_ode[threadIdx.x];
        sBo[threadIdx.x] = b_ode[threadIdx.x];
    }
    __syncthreads();

    int g = (blockIdx.x * blockDim.x + threadIdx.x) >> 5;   // node
    int f = threadIdx.x & 31;                               // feature
    if (g >= n) return;
    size_t base = (size_t)g * HID;
    float hn_self = hn_cur[base + f];

    // ---- gather aggregation, positive graph ----
    float accp = invdegP[g] * hn_self;
    {
        int beg = rpP[g], end = rpP[g + 1];
        for (int e0 = beg; e0 < end; e0 += 32) {
            int idx = e0 + f;
            bool v = idx < end;
            int   jj = v ? colP[idx] : 0;
            float cc = v ? cofP[idx] : 0.0f;
            #pragma unroll
            for (int u = 0; u < 32; ++u) {
                int j   = __shfl(jj, u, 32);
                float c = __shfl(cc, u, 32);
                accp += c * hn_cur[(size_t)j * HID + f];
            }
        }
    }
    // ---- gather aggregation, negative graph ----
    float accn = invdegN[g] * hn_self;
    {
        int beg = rpN[g], end = rpN[g + 1];
        for (int e0 = beg; e0 < end; e0 += 32) {
            int idx = e0 + f;
            bool v = idx < end;
            int   jj = v ? colN[idx] : 0;
            float cc = v ? cofN[idx] : 0.0f;
            #pragma unroll
            for (int u = 0; u < 32; ++u) {
                int j   = __shfl(jj, u, 32);
                float c = __shfl(cc, u, 32);
                accn += c * hn_cur[(size_t)j * HID + f];
            }
        }
    }

    // ---- combined matmul: val = cb + aggp @ Wpp + aggn @ Wnn ----
    float val = sCb[f];
    #pragma unroll
    for (int k = 0; k < HID; ++k) {
        float apk = __shfl(accp, k, 32);
        float ank = __shfl(accn, k, 32);
        val += apk * sWp[k][f] + ank * sWn[k][f];
    }

    // ---- k = clip(tanh(val) - 0.1*hn, -50, 50) ----
    float kv = tanhf(val) - 0.1f * hn_self;
    kv = fminf(fmaxf(kv, -50.0f), 50.0f);

    // ---- RK4 stage update ----
    const float dt = (t[1] - t[0]) * 0.125f;
    float hb = h[base + f];
    float hnext;
    if (STAGE == 0) {
        kacc[base + f] = kv;
        hnext = hb + 0.5f * dt * kv;
    } else if (STAGE == 1) {
        kacc[base + f] += 2.0f * kv;
        hnext = hb + 0.5f * dt * kv;
    } else if (STAGE == 2) {
        kacc[base + f] += 2.0f * kv;
        hnext = hb + dt * kv;
    } else {
        float ka = kacc[base + f];
        float hnew = hb + (dt * (1.0f / 6.0f)) * (ka + kv);
        if (LAST) {
            out[base + f] = hnew;
            return;
        }
        h[base + f] = hnew;
        hnext = hnew;
    }

    // ---- hn_next = LN(hnext; g_ode, b_ode) over the 32 lanes ----
    float m = hnext;
    #pragma unroll
    for (int off = 16; off > 0; off >>= 1) m += __shfl_xor(m, off, 32);
    m *= (1.0f / HID);
    float d = hnext - m;
    float v2 = d * d;
    #pragma unroll
    for (int off = 16; off > 0; off >>= 1) v2 += __shfl_xor(v2, off, 32);
    float rs = rsqrtf(v2 * (1.0f / HID) + 1e-5f);
    hn_next[base + f] = d * rs * sGo[f] + sBo[f];
}

// ---------------------------------------------------------------------------

extern "C" void kernel_launch(void* const* d_in, const int* in_sizes, int n_in,
                              void* d_out, int out_size, void* d_ws, size_t ws_size,
                              hipStream_t stream) {
    const float* x      = (const float*)d_in[0];
    const int*   eip    = (const int*)d_in[1];
    const int*   ein    = (const int*)d_in[2];
    const float* t      = (const float*)d_in[3];
    const float* w_enc  = (const float*)d_in[4];
    const float* b_enc  = (const float*)d_in[5];
    const float* g_feat = (const float*)d_in[6];
    const float* b_feat = (const float*)d_in[7];
    const float* w_pos  = (const float*)d_in[8];
    const float* b_pos  = (const float*)d_in[9];
    const float* w_neg  = (const float*)d_in[10];
    const float* b_neg  = (const float*)d_in[11];
    const float* w_psi  = (const float*)d_in[12];
    const float* g_ode  = (const float*)d_in[13];
    const float* b_ode  = (const float*)d_in[14];

    const int n = in_sizes[0] / NFEAT;      // 100000
    const int E = in_sizes[1] / 2;          // 1600000

    char* p = (char*)d_ws;
    auto carve = [&](size_t bytes) {
        void* r = (void*)p;
        p += (bytes + 255) & ~(size_t)255;
        return r;
    };
    float* h       = (float*)carve((size_t)n * HID * 4);
    float* hnA     = (float*)carve((size_t)n * HID * 4);
    float* hnB     = (float*)carve((size_t)n * HID * 4);
    float* kacc    = (float*)carve((size_t)n * HID * 4);
    float* dinvP   = (float*)carve((size_t)n * 4);
    float* invdegP = (float*)carve((size_t)n * 4);
    float* dinvN   = (float*)carve((size_t)n * 4);
    float* invdegN = (float*)carve((size_t)n * 4);
    int*   cntP    = (int*)carve((size_t)n * 4);
    int*   cntN    = (int*)carve((size_t)n * 4);
    int*   rpP     = (int*)carve((size_t)(n + 1) * 4);
    int*   rpN     = (int*)carve((size_t)(n + 1) * 4);
    int*   curP    = (int*)carve((size_t)n * 4);
    int*   curN    = (int*)carve((size_t)n * 4);
    int*   colP    = (int*)carve((size_t)E * 4);
    int*   colN    = (int*)carve((size_t)E * 4);
    float* cofP    = (float*)carve((size_t)E * 4);
    float* cofN    = (float*)carve((size_t)E * 4);
    float* wpp     = (float*)carve((size_t)HID * HID * 4);
    float* wnn     = (float*)carve((size_t)HID * HID * 4);
    float* cbias   = (float*)carve((size_t)HID * 4);
    (void)ws_size; (void)n_in; (void)out_size;

    const int* srcP = eip;
    const int* dstP = eip + E;
    const int* srcN = ein;
    const int* dstN = ein + E;

    // --- graph preprocessing (amortized over 32 fused evals) ---
    hipMemsetAsync(cntP, 0, (size_t)n * 4, stream);
    hipMemsetAsync(cntN, 0, (size_t)n * 4, stream);
    hist_kernel<<<2048, 256, 0, stream>>>(dstP, dstN, cntP, cntN, E);
    deg_kernel<<<(n + 255) / 256, 256, 0, stream>>>(cntP, cntN, dinvP, invdegP, dinvN, invdegN, n);
    scan_kernel<<<2, 1024, 0, stream>>>(cntP, cntN, rpP, rpN, n);
    hipMemcpyAsync(curP, rpP, (size_t)n * 4, hipMemcpyDeviceToDevice, stream);
    hipMemcpyAsync(curN, rpN, (size_t)n * 4, hipMemcpyDeviceToDevice, stream);
    fill_kernel<<<2048, 256, 0, stream>>>(srcP, dstP, srcN, dstN, dinvP, dinvN,
                                          curP, curN, colP, cofP, colN, cofN, E);
    wcomb_kernel<<<1, 1024, 0, stream>>>(w_pos, b_pos, w_neg, b_neg, w_psi, wpp, wnn, cbias);

    // --- encoder: h0 and its ode-LN (into hnA) ---
    encoder_kernel<<<(n + 255) / 256, 256, 0, stream>>>(x, w_enc, b_enc, g_feat, b_feat,
                                                        g_ode, b_ode, h, hnA, n);

    // --- 8 RK4 steps x 4 stages, hn ping-pong ---
    const int fg = (n * HID + 255) / 256;   // 32 lanes per node
    float* cur = hnA;
    float* nxt = hnB;
    for (int s = 0; s < 8; ++s) {
        for (int st = 0; st < 4; ++st) {
            bool last = (s == 7 && st == 3);
            if (st == 0)
                fused_kernel<0, false><<<fg, 256, 0, stream>>>(cur, nxt, rpP, colP, cofP, invdegP,
                    rpN, colN, cofN, invdegN, wpp, wnn, cbias, g_ode, b_ode, t, h, kacc,
                    (float*)d_out, n);
            else if (st == 1)
                fused_kernel<1, false><<<fg, 256, 0, stream>>>(cur, nxt, rpP, colP, cofP, invdegP,
                    rpN, colN, cofN, invdegN, wpp, wnn, cbias, g_ode, b_ode, t, h, kacc,
                    (float*)d_out, n);
            else if (st == 2)
                fused_kernel<2, false><<<fg, 256, 0, stream>>>(cur, nxt, rpP, colP, cofP, invdegP,
                    rpN, colN, cofN, invdegN, wpp, wnn, cbias, g_ode, b_ode, t, h, kacc,
                    (float*)d_out, n);
            else if (!last)
                fused_kernel<3, false><<<fg, 256, 0, stream>>>(cur, nxt, rpP, colP, cofP, invdegP,
                    rpN, colN, cofN, invdegN, wpp, wnn, cbias, g_ode, b_ode, t, h, kacc,
                    (float*)d_out, n);
            else
                fused_kernel<3, true><<<fg, 256, 0, stream>>>(cur, nxt, rpP, colP, cofP, invdegP,
                    rpN, colN, cofN, invdegN, wpp, wnn, cbias, g_ode, b_ode, t, h, kacc,
                    (float*)d_out, n);
            float* tmp = cur; cur = nxt; nxt = tmp;
        }
    }
}

// Round 9
// 3896.758 us; speedup vs baseline: 1.5367x; 1.5367x over previous
//
#include <hip/hip_runtime.h>

#define HID 32
#define NFEAT 64

// ---------------------------------------------------------------------------
// Graph preprocessing (loop-invariant, rebuilt every launch)
// ---------------------------------------------------------------------------

__global__ void hist_kernel(const int* __restrict__ dstP, const int* __restrict__ dstN,
                            int* __restrict__ cntP, int* __restrict__ cntN, int E) {
    int stride = gridDim.x * blockDim.x;
    for (int idx = blockIdx.x * blockDim.x + threadIdx.x; idx < 2 * E; idx += stride) {
        if (idx < E) atomicAdd(&cntP[dstP[idx]], 1);
        else         atomicAdd(&cntN[dstN[idx - E]], 1);
    }
}

__global__ void deg_kernel(const int* __restrict__ cntP, const int* __restrict__ cntN,
                           float* __restrict__ dinvP, float* __restrict__ invdegP,
                           float* __restrict__ dinvN, float* __restrict__ invdegN, int n) {
    int i = blockIdx.x * blockDim.x + threadIdx.x;
    if (i >= n) return;
    float dp = (float)cntP[i] + 1.0f;
    dinvP[i] = rsqrtf(dp);
    invdegP[i] = 1.0f / dp;
    float dn = (float)cntN[i] + 1.0f;
    dinvN[i] = rsqrtf(dn);
    invdegN[i] = 1.0f / dn;
}

// Exclusive scan of cnt -> row_ptr AND cur (one block per graph).
__global__ void scan_kernel(const int* __restrict__ cntP, const int* __restrict__ cntN,
                            int* __restrict__ rpP, int* __restrict__ rpN,
                            int* __restrict__ curP, int* __restrict__ curN, int n) {
    const int* cnt = blockIdx.x ? cntN : cntP;
    int* rp  = blockIdx.x ? rpN  : rpP;
    int* cur = blockIdx.x ? curN : curP;
    __shared__ int buf[1024];
    __shared__ int carry;
    int tid = threadIdx.x;
    if (tid == 0) carry = 0;
    __syncthreads();
    for (int base = 0; base < n; base += 1024) {
        int i = base + tid;
        int v = (i < n) ? cnt[i] : 0;
        buf[tid] = v;
        __syncthreads();
        for (int off = 1; off < 1024; off <<= 1) {
            int t = (tid >= off) ? buf[tid - off] : 0;
            __syncthreads();
            buf[tid] += t;
            __syncthreads();
        }
        int c = carry;
        if (i < n) {
            int ex = c + buf[tid] - v;   // exclusive
            rp[i]  = ex;
            cur[i] = ex;
        }
        __syncthreads();
        if (tid == 1023) carry = c + buf[1023];
        __syncthreads();
    }
    if (tid == 0) rp[n] = carry;
}

// Packed edge record: .x = src node, .y = float coef bits. One 8B store/edge.
__global__ void fill_kernel(const int* __restrict__ srcP, const int* __restrict__ dstP,
                            const int* __restrict__ srcN, const int* __restrict__ dstN,
                            const float* __restrict__ dinvP, const float* __restrict__ dinvN,
                            int* __restrict__ curP, int* __restrict__ curN,
                            int2* __restrict__ edP, int2* __restrict__ edN, int E) {
    int stride = gridDim.x * blockDim.x;
    for (int idx = blockIdx.x * blockDim.x + threadIdx.x; idx < 2 * E; idx += stride) {
        if (idx < E) {
            int s = srcP[idx], d = dstP[idx];
            int p = atomicAdd(&curP[d], 1);
            edP[p] = make_int2(s, __float_as_int(dinvP[s] * dinvP[d]));
        } else {
            int e = idx - E;
            int s = srcN[e], d = dstN[e];
            int p = atomicAdd(&curN[d], 1);
            edN[p] = make_int2(s, __float_as_int(dinvN[s] * dinvN[d]));
        }
    }
}

// ---------------------------------------------------------------------------
// Combined weights: Wpp = Wp @ Psi_top, Wnn = Wn @ Psi_bot,
// cbias = bp @ Psi_top + bn @ Psi_bot.   (one 1024-thread block, runs once)
// ---------------------------------------------------------------------------

__global__ void wcomb_kernel(const float* __restrict__ wp, const float* __restrict__ bp,
                             const float* __restrict__ wn, const float* __restrict__ bn,
                             const float* __restrict__ psi,
                             float* __restrict__ wpp, float* __restrict__ wnn,
                             float* __restrict__ cb) {
    int tid = threadIdx.x;
    int j = tid >> 5, f = tid & 31;
    float sp = 0.f, sn = 0.f;
    #pragma unroll
    for (int k = 0; k < HID; ++k) {
        sp += wp[j * HID + k] * psi[k * HID + f];
        sn += wn[j * HID + k] * psi[(HID + k) * HID + f];
    }
    wpp[j * HID + f] = sp;
    wnn[j * HID + f] = sn;
    if (j == 0) {
        float s = 0.f;
        #pragma unroll
        for (int k = 0; k < HID; ++k)
            s += bp[k] * psi[k * HID + f] + bn[k] * psi[(HID + k) * HID + f];
        cb[f] = s;
    }
}

// ---------------------------------------------------------------------------
// Encoder: h0 = LN(x @ w_enc + b_enc; g_feat,b_feat); hn = LN(h0; g_ode,b_ode)
// ---------------------------------------------------------------------------

__global__ __launch_bounds__(256) void encoder_kernel(
        const float* __restrict__ x, const float* __restrict__ w_enc,
        const float* __restrict__ b_enc, const float* __restrict__ g_feat,
        const float* __restrict__ b_feat, const float* __restrict__ g_ode,
        const float* __restrict__ b_ode,
        float* __restrict__ h, float* __restrict__ hn, int n) {
    __shared__ float sW[NFEAT][HID];
    __shared__ float sBe[HID], sGf[HID], sBf[HID], sGo[HID], sBo[HID];
    for (int k = threadIdx.x; k < NFEAT * HID; k += blockDim.x)
        sW[k >> 5][k & 31] = w_enc[k];
    if (threadIdx.x < HID) {
        sBe[threadIdx.x] = b_enc[threadIdx.x];
        sGf[threadIdx.x] = g_feat[threadIdx.x];
        sBf[threadIdx.x] = b_feat[threadIdx.x];
        sGo[threadIdx.x] = g_ode[threadIdx.x];
        sBo[threadIdx.x] = b_ode[threadIdx.x];
    }
    __syncthreads();
    int i = blockIdx.x * blockDim.x + threadIdx.x;
    if (i >= n) return;

    float acc[HID];
    #pragma unroll
    for (int f = 0; f < HID; ++f) acc[f] = sBe[f];
    const float4* xr = reinterpret_cast<const float4*>(x + (size_t)i * NFEAT);
    #pragma unroll 2
    for (int q = 0; q < NFEAT / 4; ++q) {
        float4 a = xr[q];
        #pragma unroll
        for (int r = 0; r < 4; ++r) {
            float av = (r == 0) ? a.x : (r == 1) ? a.y : (r == 2) ? a.z : a.w;
            const float4* wr = reinterpret_cast<const float4*>(sW[4 * q + r]);
            #pragma unroll
            for (int f4 = 0; f4 < HID / 4; ++f4) {
                float4 w = wr[f4];
                acc[4 * f4 + 0] += av * w.x;
                acc[4 * f4 + 1] += av * w.y;
                acc[4 * f4 + 2] += av * w.z;
                acc[4 * f4 + 3] += av * w.w;
            }
        }
    }
    // LN (feat)
    float m = 0.f;
    #pragma unroll
    for (int f = 0; f < HID; ++f) m += acc[f];
    m *= (1.0f / HID);
    float var = 0.f;
    #pragma unroll
    for (int f = 0; f < HID; ++f) { float d = acc[f] - m; var += d * d; }
    var *= (1.0f / HID);
    float rs = rsqrtf(var + 1e-5f);
    #pragma unroll
    for (int f = 0; f < HID; ++f) acc[f] = (acc[f] - m) * rs * sGf[f] + sBf[f];

    float4* hw = reinterpret_cast<float4*>(h + (size_t)i * HID);
    #pragma unroll
    for (int q = 0; q < HID / 4; ++q)
        hw[q] = make_float4(acc[4*q], acc[4*q+1], acc[4*q+2], acc[4*q+3]);

    // LN (ode) -> hn
    m = 0.f;
    #pragma unroll
    for (int f = 0; f < HID; ++f) m += acc[f];
    m *= (1.0f / HID);
    var = 0.f;
    #pragma unroll
    for (int f = 0; f < HID; ++f) { float d = acc[f] - m; var += d * d; }
    var *= (1.0f / HID);
    rs = rsqrtf(var + 1e-5f);
    float4* hnw = reinterpret_cast<float4*>(hn + (size_t)i * HID);
    #pragma unroll
    for (int q = 0; q < HID / 4; ++q)
        hnw[q] = make_float4((acc[4*q+0] - m) * rs * sGo[4*q+0] + sBo[4*q+0],
                             (acc[4*q+1] - m) * rs * sGo[4*q+1] + sBo[4*q+1],
                             (acc[4*q+2] - m) * rs * sGo[4*q+2] + sBo[4*q+2],
                             (acc[4*q+3] - m) * rs * sGo[4*q+3] + sBo[4*q+3]);
}

// ---------------------------------------------------------------------------
// Fused ODE-eval kernel: one 32-lane group per node (lane f = feature f).
// Gather loop: dynamic trip count, 8-wide unroll with 8 independent
// accumulators (8 gathers in flight), edge metadata read group-uniform
// (one int2 per edge, L1-resident). Then shfl matmul, tanh/clip, RK4,
// LN(next) -> hn_next. hn ping-pongs across evals (no read/write race).
// ---------------------------------------------------------------------------

template<int STAGE, bool LAST>
__global__ __launch_bounds__(256) void fused_kernel(
        const float* __restrict__ hn_cur, float* __restrict__ hn_next,
        const int* __restrict__ rpP, const int2* __restrict__ edP,
        const float* __restrict__ invdegP,
        const int* __restrict__ rpN, const int2* __restrict__ edN,
        const float* __restrict__ invdegN,
        const float* __restrict__ wpp, const float* __restrict__ wnn,
        const float* __restrict__ cb,
        const float* __restrict__ g_ode, const float* __restrict__ b_ode,
        const float* __restrict__ t,
        float* __restrict__ h, float* __restrict__ kacc,
        float* __restrict__ out, int n) {
    __shared__ float sWp[HID][HID];
    __shared__ float sWn[HID][HID];
    __shared__ float sCb[HID], sGo[HID], sBo[HID];
    for (int k = threadIdx.x; k < HID * HID; k += blockDim.x) {
        sWp[k >> 5][k & 31] = wpp[k];
        sWn[k >> 5][k & 31] = wnn[k];
    }
    if (threadIdx.x < HID) {
        sCb[threadIdx.x] = cb[threadIdx.x];
        sGo[threadIdx.x] = g_ode[threadIdx.x];
        sBo[threadIdx.x] = b_ode[threadIdx.x];
    }
    __syncthreads();

    int g = (blockIdx.x * blockDim.x + threadIdx.x) >> 5;   // node
    int f = threadIdx.x & 31;                               // feature
    if (g >= n) return;
    size_t base = (size_t)g * HID;
    float hn_self = hn_cur[base + f];

    // ---- gather aggregation, positive graph ----
    float accp = invdegP[g] * hn_self;
    {
        int e = rpP[g];
        const int end = rpP[g + 1];
        float a0 = 0.f, a1 = 0.f, a2 = 0.f, a3 = 0.f;
        float a4 = 0.f, a5 = 0.f, a6 = 0.f, a7 = 0.f;
        for (; e + 8 <= end; e += 8) {
            int2 m0 = edP[e+0]; int2 m1 = edP[e+1]; int2 m2 = edP[e+2]; int2 m3 = edP[e+3];
            int2 m4 = edP[e+4]; int2 m5 = edP[e+5]; int2 m6 = edP[e+6]; int2 m7 = edP[e+7];
            a0 += __int_as_float(m0.y) * hn_cur[(size_t)m0.x * HID + f];
            a1 += __int_as_float(m1.y) * hn_cur[(size_t)m1.x * HID + f];
            a2 += __int_as_float(m2.y) * hn_cur[(size_t)m2.x * HID + f];
            a3 += __int_as_float(m3.y) * hn_cur[(size_t)m3.x * HID + f];
            a4 += __int_as_float(m4.y) * hn_cur[(size_t)m4.x * HID + f];
            a5 += __int_as_float(m5.y) * hn_cur[(size_t)m5.x * HID + f];
            a6 += __int_as_float(m6.y) * hn_cur[(size_t)m6.x * HID + f];
            a7 += __int_as_float(m7.y) * hn_cur[(size_t)m7.x * HID + f];
        }
        if (e + 4 <= end) {
            int2 m0 = edP[e+0]; int2 m1 = edP[e+1]; int2 m2 = edP[e+2]; int2 m3 = edP[e+3];
            a0 += __int_as_float(m0.y) * hn_cur[(size_t)m0.x * HID + f];
            a1 += __int_as_float(m1.y) * hn_cur[(size_t)m1.x * HID + f];
            a2 += __int_as_float(m2.y) * hn_cur[(size_t)m2.x * HID + f];
            a3 += __int_as_float(m3.y) * hn_cur[(size_t)m3.x * HID + f];
            e += 4;
        }
        for (; e < end; ++e) {
            int2 m = edP[e];
            a0 += __int_as_float(m.y) * hn_cur[(size_t)m.x * HID + f];
        }
        accp += ((a0 + a1) + (a2 + a3)) + ((a4 + a5) + (a6 + a7));
    }
    // ---- gather aggregation, negative graph ----
    float accn = invdegN[g] * hn_self;
    {
        int e = rpN[g];
        const int end = rpN[g + 1];
        float a0 = 0.f, a1 = 0.f, a2 = 0.f, a3 = 0.f;
        float a4 = 0.f, a5 = 0.f, a6 = 0.f, a7 = 0.f;
        for (; e + 8 <= end; e += 8) {
            int2 m0 = edN[e+0]; int2 m1 = edN[e+1]; int2 m2 = edN[e+2]; int2 m3 = edN[e+3];
            int2 m4 = edN[e+4]; int2 m5 = edN[e+5]; int2 m6 = edN[e+6]; int2 m7 = edN[e+7];
            a0 += __int_as_float(m0.y) * hn_cur[(size_t)m0.x * HID + f];
            a1 += __int_as_float(m1.y) * hn_cur[(size_t)m1.x * HID + f];
            a2 += __int_as_float(m2.y) * hn_cur[(size_t)m2.x * HID + f];
            a3 += __int_as_float(m3.y) * hn_cur[(size_t)m3.x * HID + f];
            a4 += __int_as_float(m4.y) * hn_cur[(size_t)m4.x * HID + f];
            a5 += __int_as_float(m5.y) * hn_cur[(size_t)m5.x * HID + f];
            a6 += __int_as_float(m6.y) * hn_cur[(size_t)m6.x * HID + f];
            a7 += __int_as_float(m7.y) * hn_cur[(size_t)m7.x * HID + f];
        }
        if (e + 4 <= end) {
            int2 m0 = edN[e+0]; int2 m1 = edN[e+1]; int2 m2 = edN[e+2]; int2 m3 = edN[e+3];
            a0 += __int_as_float(m0.y) * hn_cur[(size_t)m0.x * HID + f];
            a1 += __int_as_float(m1.y) * hn_cur[(size_t)m1.x * HID + f];
            a2 += __int_as_float(m2.y) * hn_cur[(size_t)m2.x * HID + f];
            a3 += __int_as_float(m3.y) * hn_cur[(size_t)m3.x * HID + f];
            e += 4;
        }
        for (; e < end; ++e) {
            int2 m = edN[e];
            a0 += __int_as_float(m.y) * hn_cur[(size_t)m.x * HID + f];
        }
        accn += ((a0 + a1) + (a2 + a3)) + ((a4 + a5) + (a6 + a7));
    }

    // ---- combined matmul: val = cb + aggp @ Wpp + aggn @ Wnn ----
    float val = sCb[f];
    #pragma unroll
    for (int k = 0; k < HID; ++k) {
        float apk = __shfl(accp, k, 32);
        float ank = __shfl(accn, k, 32);
        val += apk * sWp[k][f] + ank * sWn[k][f];
    }

    // ---- k = clip(tanh(val) - 0.1*hn, -50, 50) ----
    float kv = tanhf(val) - 0.1f * hn_self;
    kv = fminf(fmaxf(kv, -50.0f), 50.0f);

    // ---- RK4 stage update ----
    const float dt = (t[1] - t[0]) * 0.125f;
    float hb = h[base + f];
    float hnext;
    if (STAGE == 0) {
        kacc[base + f] = kv;
        hnext = hb + 0.5f * dt * kv;
    } else if (STAGE == 1) {
        kacc[base + f] += 2.0f * kv;
        hnext = hb + 0.5f * dt * kv;
    } else if (STAGE == 2) {
        kacc[base + f] += 2.0f * kv;
        hnext = hb + dt * kv;
    } else {
        float ka = kacc[base + f];
        float hnew = hb + (dt * (1.0f / 6.0f)) * (ka + kv);
        if (LAST) {
            out[base + f] = hnew;
            return;
        }
        h[base + f] = hnew;
        hnext = hnew;
    }

    // ---- hn_next = LN(hnext; g_ode, b_ode) over the 32 lanes ----
    float m = hnext;
    #pragma unroll
    for (int off = 16; off > 0; off >>= 1) m += __shfl_xor(m, off, 32);
    m *= (1.0f / HID);
    float d = hnext - m;
    float v2 = d * d;
    #pragma unroll
    for (int off = 16; off > 0; off >>= 1) v2 += __shfl_xor(v2, off, 32);
    float rs = rsqrtf(v2 * (1.0f / HID) + 1e-5f);
    hn_next[base + f] = d * rs * sGo[f] + sBo[f];
}

// ---------------------------------------------------------------------------

extern "C" void kernel_launch(void* const* d_in, const int* in_sizes, int n_in,
                              void* d_out, int out_size, void* d_ws, size_t ws_size,
                              hipStream_t stream) {
    const float* x      = (const float*)d_in[0];
    const int*   eip    = (const int*)d_in[1];
    const int*   ein    = (const int*)d_in[2];
    const float* t      = (const float*)d_in[3];
    const float* w_enc  = (const float*)d_in[4];
    const float* b_enc  = (const float*)d_in[5];
    const float* g_feat = (const float*)d_in[6];
    const float* b_feat = (const float*)d_in[7];
    const float* w_pos  = (const float*)d_in[8];
    const float* b_pos  = (const float*)d_in[9];
    const float* w_neg  = (const float*)d_in[10];
    const float* b_neg  = (const float*)d_in[11];
    const float* w_psi  = (const float*)d_in[12];
    const float* g_ode  = (const float*)d_in[13];
    const float* b_ode  = (const float*)d_in[14];

    const int n = in_sizes[0] / NFEAT;      // 100000
    const int E = in_sizes[1] / 2;          // 1600000

    char* p = (char*)d_ws;
    auto carve = [&](size_t bytes) {
        void* r = (void*)p;
        p += (bytes + 255) & ~(size_t)255;
        return r;
    };
    float* h       = (float*)carve((size_t)n * HID * 4);
    float* hnA     = (float*)carve((size_t)n * HID * 4);
    float* hnB     = (float*)carve((size_t)n * HID * 4);
    float* kacc    = (float*)carve((size_t)n * HID * 4);
    float* dinvP   = (float*)carve((size_t)n * 4);
    float* invdegP = (float*)carve((size_t)n * 4);
    float* dinvN   = (float*)carve((size_t)n * 4);
    float* invdegN = (float*)carve((size_t)n * 4);
    int*   cntP    = (int*)carve((size_t)n * 4);
    int*   cntN    = (int*)carve((size_t)n * 4);
    int*   rpP     = (int*)carve((size_t)(n + 1) * 4);
    int*   rpN     = (int*)carve((size_t)(n + 1) * 4);
    int*   curP    = (int*)carve((size_t)n * 4);
    int*   curN    = (int*)carve((size_t)n * 4);
    int2*  edP     = (int2*)carve((size_t)E * 8);
    int2*  edN     = (int2*)carve((size_t)E * 8);
    float* wpp     = (float*)carve((size_t)HID * HID * 4);
    float* wnn     = (float*)carve((size_t)HID * HID * 4);
    float* cbias   = (float*)carve((size_t)HID * 4);
    (void)ws_size; (void)n_in; (void)out_size;

    const int* srcP = eip;
    const int* dstP = eip + E;
    const int* srcN = ein;
    const int* dstN = ein + E;

    // --- graph preprocessing (amortized over 32 fused evals) ---
    hipMemsetAsync(cntP, 0, (size_t)n * 4, stream);
    hipMemsetAsync(cntN, 0, (size_t)n * 4, stream);
    hist_kernel<<<2048, 256, 0, stream>>>(dstP, dstN, cntP, cntN, E);
    deg_kernel<<<(n + 255) / 256, 256, 0, stream>>>(cntP, cntN, dinvP, invdegP, dinvN, invdegN, n);
    scan_kernel<<<2, 1024, 0, stream>>>(cntP, cntN, rpP, rpN, curP, curN, n);
    fill_kernel<<<2048, 256, 0, stream>>>(srcP, dstP, srcN, dstN, dinvP, dinvN,
                                          curP, curN, edP, edN, E);
    wcomb_kernel<<<1, 1024, 0, stream>>>(w_pos, b_pos, w_neg, b_neg, w_psi, wpp, wnn, cbias);

    // --- encoder: h0 and its ode-LN (into hnA) ---
    encoder_kernel<<<(n + 255) / 256, 256, 0, stream>>>(x, w_enc, b_enc, g_feat, b_feat,
                                                        g_ode, b_ode, h, hnA, n);

    // --- 8 RK4 steps x 4 stages, hn ping-pong ---
    const int fg = (n * HID + 255) / 256;   // 32 lanes per node
    float* cur = hnA;
    float* nxt = hnB;
    for (int s = 0; s < 8; ++s) {
        for (int st = 0; st < 4; ++st) {
            bool last = (s == 7 && st == 3);
            if (st == 0)
                fused_kernel<0, false><<<fg, 256, 0, stream>>>(cur, nxt, rpP, edP, invdegP,
                    rpN, edN, invdegN, wpp, wnn, cbias, g_ode, b_ode, t, h, kacc,
                    (float*)d_out, n);
            else if (st == 1)
                fused_kernel<1, false><<<fg, 256, 0, stream>>>(cur, nxt, rpP, edP, invdegP,
                    rpN, edN, invdegN, wpp, wnn, cbias, g_ode, b_ode, t, h, kacc,
                    (float*)d_out, n);
            else if (st == 2)
                fused_kernel<2, false><<<fg, 256, 0, stream>>>(cur, nxt, rpP, edP, invdegP,
                    rpN, edN, invdegN, wpp, wnn, cbias, g_ode, b_ode, t, h, kacc,
                    (float*)d_out, n);
            else if (!last)
                fused_kernel<3, false><<<fg, 256, 0, stream>>>(cur, nxt, rpP, edP, invdegP,
                    rpN, edN, invdegN, wpp, wnn, cbias, g_ode, b_ode, t, h, kacc,
                    (float*)d_out, n);
            else
                fused_kernel<3, true><<<fg, 256, 0, stream>>>(cur, nxt, rpP, edP, invdegP,
                    rpN, edN, invdegN, wpp, wnn, cbias, g_ode, b_ode, t, h, kacc,
                    (float*)d_out, n);
            float* tmp = cur; cur = nxt; nxt = tmp;
        }
    }
}

// Round 11
// 3685.995 us; speedup vs baseline: 1.6246x; 1.0572x over previous
//
#include <hip/hip_runtime.h>
#include <hip/hip_fp16.h>

#define HID 32
#define NFEAT 64

// ---------------------------------------------------------------------------
// Graph preprocessing (loop-invariant, rebuilt every launch)
// ---------------------------------------------------------------------------

__global__ void hist_kernel(const int* __restrict__ dstP, const int* __restrict__ dstN,
                            int* __restrict__ cntP, int* __restrict__ cntN, int E) {
    int stride = gridDim.x * blockDim.x;
    for (int idx = blockIdx.x * blockDim.x + threadIdx.x; idx < 2 * E; idx += stride) {
        if (idx < E) atomicAdd(&cntP[dstP[idx]], 1);
        else         atomicAdd(&cntN[dstN[idx - E]], 1);
    }
}

__global__ void deg_kernel(const int* __restrict__ cntP, const int* __restrict__ cntN,
                           float* __restrict__ dinvP, float* __restrict__ invdegP,
                           float* __restrict__ dinvN, float* __restrict__ invdegN, int n) {
    int i = blockIdx.x * blockDim.x + threadIdx.x;
    if (i >= n) return;
    float dp = (float)cntP[i] + 1.0f;
    dinvP[i] = rsqrtf(dp);
    invdegP[i] = 1.0f / dp;
    float dn = (float)cntN[i] + 1.0f;
    dinvN[i] = rsqrtf(dn);
    invdegN[i] = 1.0f / dn;
}

// ---------------------------------------------------------------------------
// 3-phase multi-block exclusive scan (1024 elems per block, 256 threads x 4).
// A: local exclusive scan into rp + block totals. B: scan totals (one block
// per graph, nb<=256), write rp[n]. C: add block offsets, write rp and cur.
// ---------------------------------------------------------------------------

__global__ __launch_bounds__(256) void scanA_kernel(
        const int* __restrict__ cntP, const int* __restrict__ cntN,
        int* __restrict__ rpP, int* __restrict__ rpN,
        int* __restrict__ partials, int n, int nb) {
    int gb = blockIdx.x;
    int graph = (gb >= nb) ? 1 : 0;
    int b = graph ? gb - nb : gb;
    const int* cnt = graph ? cntN : cntP;
    int* rp = graph ? rpN : rpP;
    __shared__ int tsum[256];
    int tid = threadIdx.x;
    int base = b * 1024 + tid * 4;
    int v[4];
    int s = 0;
    #pragma unroll
    for (int k = 0; k < 4; ++k) {
        int i = base + k;
        v[k] = (i < n) ? cnt[i] : 0;
        s += v[k];
    }
    tsum[tid] = s;
    __syncthreads();
    for (int off = 1; off < 256; off <<= 1) {
        int t = (tid >= off) ? tsum[tid - off] : 0;
        __syncthreads();
        tsum[tid] += t;
        __syncthreads();
    }
    int ex = tsum[tid] - s;
    #pragma unroll
    for (int k = 0; k < 4; ++k) {
        int i = base + k;
        if (i < n) rp[i] = ex;
        ex += v[k];
    }
    if (tid == 255) partials[gb] = tsum[255];
}

__global__ __launch_bounds__(256) void scanB_kernel(
        int* __restrict__ partials, int* __restrict__ rpP, int* __restrict__ rpN,
        int n, int nb) {
    int graph = blockIdx.x;
    int* part = partials + graph * nb;
    __shared__ int buf[256];
    int tid = threadIdx.x;
    int v = (tid < nb) ? part[tid] : 0;
    buf[tid] = v;
    __syncthreads();
    for (int off = 1; off < 256; off <<= 1) {
        int t = (tid >= off) ? buf[tid - off] : 0;
        __syncthreads();
        buf[tid] += t;
        __syncthreads();
    }
    if (tid < nb) part[tid] = buf[tid] - v;   // exclusive
    if (tid == 255) {
        int* rp = graph ? rpN : rpP;
        rp[n] = buf[255];                      // total edge count
    }
}

__global__ __launch_bounds__(256) void scanC_kernel(
        int* __restrict__ rpP, int* __restrict__ rpN,
        int* __restrict__ curP, int* __restrict__ curN,
        const int* __restrict__ partials, int n, int nb) {
    int gb = blockIdx.x;
    int graph = (gb >= nb) ? 1 : 0;
    int b = graph ? gb - nb : gb;
    int* rp  = graph ? rpN  : rpP;
    int* cur = graph ? curN : curP;
    int off = partials[gb];
    int base = b * 1024 + threadIdx.x * 4;
    #pragma unroll
    for (int k = 0; k < 4; ++k) {
        int i = base + k;
        if (i < n) {
            int val = rp[i] + off;
            rp[i]  = val;
            cur[i] = val;
        }
    }
}

// Packed edge record: .x = src node, .y = float coef bits. One 8B store/edge.
__global__ void fill_kernel(const int* __restrict__ srcP, const int* __restrict__ dstP,
                            const int* __restrict__ srcN, const int* __restrict__ dstN,
                            const float* __restrict__ dinvP, const float* __restrict__ dinvN,
                            int* __restrict__ curP, int* __restrict__ curN,
                            int2* __restrict__ edP, int2* __restrict__ edN, int E) {
    int stride = gridDim.x * blockDim.x;
    for (int idx = blockIdx.x * blockDim.x + threadIdx.x; idx < 2 * E; idx += stride) {
        if (idx < E) {
            int s = srcP[idx], d = dstP[idx];
            int p = atomicAdd(&curP[d], 1);
            edP[p] = make_int2(s, __float_as_int(dinvP[s] * dinvP[d]));
        } else {
            int e = idx - E;
            int s = srcN[e], d = dstN[e];
            int p = atomicAdd(&curN[d], 1);
            edN[p] = make_int2(s, __float_as_int(dinvN[s] * dinvN[d]));
        }
    }
}

// ---------------------------------------------------------------------------
// Combined weights: Wpp = Wp @ Psi_top, Wnn = Wn @ Psi_bot,
// cbias = bp @ Psi_top + bn @ Psi_bot.   (one 1024-thread block, runs once)
// ---------------------------------------------------------------------------

__global__ void wcomb_kernel(const float* __restrict__ wp, const float* __restrict__ bp,
                             const float* __restrict__ wn, const float* __restrict__ bn,
                             const float* __restrict__ psi,
                             float* __restrict__ wpp, float* __restrict__ wnn,
                             float* __restrict__ cb) {
    int tid = threadIdx.x;
    int j = tid >> 5, f = tid & 31;
    float sp = 0.f, sn = 0.f;
    #pragma unroll
    for (int k = 0; k < HID; ++k) {
        sp += wp[j * HID + k] * psi[k * HID + f];
        sn += wn[j * HID + k] * psi[(HID + k) * HID + f];
    }
    wpp[j * HID + f] = sp;
    wnn[j * HID + f] = sn;
    if (j == 0) {
        float s = 0.f;
        #pragma unroll
        for (int k = 0; k < HID; ++k)
            s += bp[k] * psi[k * HID + f] + bn[k] * psi[(HID + k) * HID + f];
        cb[f] = s;
    }
}

// ---------------------------------------------------------------------------
// Encoder: h0 = LN(x @ w_enc + b_enc; g_feat,b_feat) -> h (fp32)
//          hn = LN(h0; g_ode,b_ode) -> fp16 gather table
// ---------------------------------------------------------------------------

__global__ __launch_bounds__(256) void encoder_kernel(
        const float* __restrict__ x, const float* __restrict__ w_enc,
        const float* __restrict__ b_enc, const float* __restrict__ g_feat,
        const float* __restrict__ b_feat, const float* __restrict__ g_ode,
        const float* __restrict__ b_ode,
        float* __restrict__ h, __half* __restrict__ hn, int n) {
    __shared__ float sW[NFEAT][HID];
    __shared__ float sBe[HID], sGf[HID], sBf[HID], sGo[HID], sBo[HID];
    for (int k = threadIdx.x; k < NFEAT * HID; k += blockDim.x)
        sW[k >> 5][k & 31] = w_enc[k];
    if (threadIdx.x < HID) {
        sBe[threadIdx.x] = b_enc[threadIdx.x];
        sGf[threadIdx.x] = g_feat[threadIdx.x];
        sBf[threadIdx.x] = b_feat[threadIdx.x];
        sGo[threadIdx.x] = g_ode[threadIdx.x];
        sBo[threadIdx.x] = b_ode[threadIdx.x];
    }
    __syncthreads();
    int i = blockIdx.x * blockDim.x + threadIdx.x;
    if (i >= n) return;

    float acc[HID];
    #pragma unroll
    for (int f = 0; f < HID; ++f) acc[f] = sBe[f];
    const float4* xr = reinterpret_cast<const float4*>(x + (size_t)i * NFEAT);
    #pragma unroll 2
    for (int q = 0; q < NFEAT / 4; ++q) {
        float4 a = xr[q];
        #pragma unroll
        for (int r = 0; r < 4; ++r) {
            float av = (r == 0) ? a.x : (r == 1) ? a.y : (r == 2) ? a.z : a.w;
            const float4* wr = reinterpret_cast<const float4*>(sW[4 * q + r]);
            #pragma unroll
            for (int f4 = 0; f4 < HID / 4; ++f4) {
                float4 w = wr[f4];
                acc[4 * f4 + 0] += av * w.x;
                acc[4 * f4 + 1] += av * w.y;
                acc[4 * f4 + 2] += av * w.z;
                acc[4 * f4 + 3] += av * w.w;
            }
        }
    }
    // LN (feat)
    float m = 0.f;
    #pragma unroll
    for (int f = 0; f < HID; ++f) m += acc[f];
    m *= (1.0f / HID);
    float var = 0.f;
    #pragma unroll
    for (int f = 0; f < HID; ++f) { float d = acc[f] - m; var += d * d; }
    var *= (1.0f / HID);
    float rs = rsqrtf(var + 1e-5f);
    #pragma unroll
    for (int f = 0; f < HID; ++f) acc[f] = (acc[f] - m) * rs * sGf[f] + sBf[f];

    float4* hw = reinterpret_cast<float4*>(h + (size_t)i * HID);
    #pragma unroll
    for (int q = 0; q < HID / 4; ++q)
        hw[q] = make_float4(acc[4*q], acc[4*q+1], acc[4*q+2], acc[4*q+3]);

    // LN (ode) -> hn (fp16)
    m = 0.f;
    #pragma unroll
    for (int f = 0; f < HID; ++f) m += acc[f];
    m *= (1.0f / HID);
    var = 0.f;
    #pragma unroll
    for (int f = 0; f < HID; ++f) { float d = acc[f] - m; var += d * d; }
    var *= (1.0f / HID);
    rs = rsqrtf(var + 1e-5f);
    __half2* hnw = reinterpret_cast<__half2*>(hn + (size_t)i * HID);
    #pragma unroll
    for (int q = 0; q < HID / 2; ++q) {
        float v0 = (acc[2*q+0] - m) * rs * sGo[2*q+0] + sBo[2*q+0];
        float v1 = (acc[2*q+1] - m) * rs * sGo[2*q+1] + sBo[2*q+1];
        hnw[q] = __floats2half2_rn(v0, v1);
    }
}

// ---------------------------------------------------------------------------
// Fused ODE-eval kernel: one 32-lane group per node (lane f = feature f).
// Gather over fp16 hn table (64B line per edge), 8-wide unrolled with 8
// independent accumulators. Then shfl matmul, tanh/clip, RK4, LN -> hn_next.
// hn ping-pongs across evals (no read/write race).
// ---------------------------------------------------------------------------

template<int STAGE, bool LAST>
__global__ __launch_bounds__(256) void fused_kernel(
        const __half* __restrict__ hn_cur, __half* __restrict__ hn_next,
        const int* __restrict__ rpP, const int2* __restrict__ edP,
        const float* __restrict__ invdegP,
        const int* __restrict__ rpN, const int2* __restrict__ edN,
        const float* __restrict__ invdegN,
        const float* __restrict__ wpp, const float* __restrict__ wnn,
        const float* __restrict__ cb,
        const float* __restrict__ g_ode, const float* __restrict__ b_ode,
        const float* __restrict__ t,
        float* __restrict__ h, float* __restrict__ kacc,
        float* __restrict__ out, int n) {
    __shared__ float sWp[HID][HID];
    __shared__ float sWn[HID][HID];
    __shared__ float sCb[HID], sGo[HID], sBo[HID];
    for (int k = threadIdx.x; k < HID * HID; k += blockDim.x) {
        sWp[k >> 5][k & 31] = wpp[k];
        sWn[k >> 5][k & 31] = wnn[k];
    }
    if (threadIdx.x < HID) {
        sCb[threadIdx.x] = cb[threadIdx.x];
        sGo[threadIdx.x] = g_ode[threadIdx.x];
        sBo[threadIdx.x] = b_ode[threadIdx.x];
    }
    __syncthreads();

    int g = (blockIdx.x * blockDim.x + threadIdx.x) >> 5;   // node
    int f = threadIdx.x & 31;                               // feature
    if (g >= n) return;
    size_t base = (size_t)g * HID;
    float hn_self = __half2float(hn_cur[base + f]);

    // ---- gather aggregation, positive graph ----
    float accp = invdegP[g] * hn_self;
    {
        int e = rpP[g];
        const int end = rpP[g + 1];
        float a0 = 0.f, a1 = 0.f, a2 = 0.f, a3 = 0.f;
        float a4 = 0.f, a5 = 0.f, a6 = 0.f, a7 = 0.f;
        for (; e + 8 <= end; e += 8) {
            int2 m0 = edP[e+0]; int2 m1 = edP[e+1]; int2 m2 = edP[e+2]; int2 m3 = edP[e+3];
            int2 m4 = edP[e+4]; int2 m5 = edP[e+5]; int2 m6 = edP[e+6]; int2 m7 = edP[e+7];
            a0 += __int_as_float(m0.y) * __half2float(hn_cur[(size_t)m0.x * HID + f]);
            a1 += __int_as_float(m1.y) * __half2float(hn_cur[(size_t)m1.x * HID + f]);
            a2 += __int_as_float(m2.y) * __half2float(hn_cur[(size_t)m2.x * HID + f]);
            a3 += __int_as_float(m3.y) * __half2float(hn_cur[(size_t)m3.x * HID + f]);
            a4 += __int_as_float(m4.y) * __half2float(hn_cur[(size_t)m4.x * HID + f]);
            a5 += __int_as_float(m5.y) * __half2float(hn_cur[(size_t)m5.x * HID + f]);
            a6 += __int_as_float(m6.y) * __half2float(hn_cur[(size_t)m6.x * HID + f]);
            a7 += __int_as_float(m7.y) * __half2float(hn_cur[(size_t)m7.x * HID + f]);
        }
        if (e + 4 <= end) {
            int2 m0 = edP[e+0]; int2 m1 = edP[e+1]; int2 m2 = edP[e+2]; int2 m3 = edP[e+3];
            a0 += __int_as_float(m0.y) * __half2float(hn_cur[(size_t)m0.x * HID + f]);
            a1 += __int_as_float(m1.y) * __half2float(hn_cur[(size_t)m1.x * HID + f]);
            a2 += __int_as_float(m2.y) * __half2float(hn_cur[(size_t)m2.x * HID + f]);
            a3 += __int_as_float(m3.y) * __half2float(hn_cur[(size_t)m3.x * HID + f]);
            e += 4;
        }
        for (; e < end; ++e) {
            int2 m = edP[e];
            a0 += __int_as_float(m.y) * __half2float(hn_cur[(size_t)m.x * HID + f]);
        }
        accp += ((a0 + a1) + (a2 + a3)) + ((a4 + a5) + (a6 + a7));
    }
    // ---- gather aggregation, negative graph ----
    float accn = invdegN[g] * hn_self;
    {
        int e = rpN[g];
        const int end = rpN[g + 1];
        float a0 = 0.f, a1 = 0.f, a2 = 0.f, a3 = 0.f;
        float a4 = 0.f, a5 = 0.f, a6 = 0.f, a7 = 0.f;
        for (; e + 8 <= end; e += 8) {
            int2 m0 = edN[e+0]; int2 m1 = edN[e+1]; int2 m2 = edN[e+2]; int2 m3 = edN[e+3];
            int2 m4 = edN[e+4]; int2 m5 = edN[e+5]; int2 m6 = edN[e+6]; int2 m7 = edN[e+7];
            a0 += __int_as_float(m0.y) * __half2float(hn_cur[(size_t)m0.x * HID + f]);
            a1 += __int_as_float(m1.y) * __half2float(hn_cur[(size_t)m1.x * HID + f]);
            a2 += __int_as_float(m2.y) * __half2float(hn_cur[(size_t)m2.x * HID + f]);
            a3 += __int_as_float(m3.y) * __half2float(hn_cur[(size_t)m3.x * HID + f]);
            a4 += __int_as_float(m4.y) * __half2float(hn_cur[(size_t)m4.x * HID + f]);
            a5 += __int_as_float(m5.y) * __half2float(hn_cur[(size_t)m5.x * HID + f]);
            a6 += __int_as_float(m6.y) * __half2float(hn_cur[(size_t)m6.x * HID + f]);
            a7 += __int_as_float(m7.y) * __half2float(hn_cur[(size_t)m7.x * HID + f]);
        }
        if (e + 4 <= end) {
            int2 m0 = edN[e+0]; int2 m1 = edN[e+1]; int2 m2 = edN[e+2]; int2 m3 = edN[e+3];
            a0 += __int_as_float(m0.y) * __half2float(hn_cur[(size_t)m0.x * HID + f]);
            a1 += __int_as_float(m1.y) * __half2float(hn_cur[(size_t)m1.x * HID + f]);
            a2 += __int_as_float(m2.y) * __half2float(hn_cur[(size_t)m2.x * HID + f]);
            a3 += __int_as_float(m3.y) * __half2float(hn_cur[(size_t)m3.x * HID + f]);
            e += 4;
        }
        for (; e < end; ++e) {
            int2 m = edN[e];
            a0 += __int_as_float(m.y) * __half2float(hn_cur[(size_t)m.x * HID + f]);
        }
        accn += ((a0 + a1) + (a2 + a3)) + ((a4 + a5) + (a6 + a7));
    }

    // ---- combined matmul: val = cb + aggp @ Wpp + aggn @ Wnn ----
    float val = sCb[f];
    #pragma unroll
    for (int k = 0; k < HID; ++k) {
        float apk = __shfl(accp, k, 32);
        float ank = __shfl(accn, k, 32);
        val += apk * sWp[k][f] + ank * sWn[k][f];
    }

    // ---- k = clip(tanh(val) - 0.1*hn, -50, 50) ----
    float kv = tanhf(val) - 0.1f * hn_self;
    kv = fminf(fmaxf(kv, -50.0f), 50.0f);

    // ---- RK4 stage update ----
    const float dt = (t[1] - t[0]) * 0.125f;
    float hb = h[base + f];
    float hnext;
    if (STAGE == 0) {
        kacc[base + f] = kv;
        hnext = hb + 0.5f * dt * kv;
    } else if (STAGE == 1) {
        kacc[base + f] += 2.0f * kv;
        hnext = hb + 0.5f * dt * kv;
    } else if (STAGE == 2) {
        kacc[base + f] += 2.0f * kv;
        hnext = hb + dt * kv;
    } else {
        float ka = kacc[base + f];
        float hnew = hb + (dt * (1.0f / 6.0f)) * (ka + kv);
        if (LAST) {
            out[base + f] = hnew;
            return;
        }
        h[base + f] = hnew;
        hnext = hnew;
    }

    // ---- hn_next = LN(hnext; g_ode, b_ode) over the 32 lanes -> fp16 ----
    float m = hnext;
    #pragma unroll
    for (int off = 16; off > 0; off >>= 1) m += __shfl_xor(m, off, 32);
    m *= (1.0f / HID);
    float d = hnext - m;
    float v2 = d * d;
    #pragma unroll
    for (int off = 16; off > 0; off >>= 1) v2 += __shfl_xor(v2, off, 32);
    float rs = rsqrtf(v2 * (1.0f / HID) + 1e-5f);
    hn_next[base + f] = __float2half(d * rs * sGo[f] + sBo[f]);
}

// ---------------------------------------------------------------------------

extern "C" void kernel_launch(void* const* d_in, const int* in_sizes, int n_in,
                              void* d_out, int out_size, void* d_ws, size_t ws_size,
                              hipStream_t stream) {
    const float* x      = (const float*)d_in[0];
    const int*   eip    = (const int*)d_in[1];
    const int*   ein    = (const int*)d_in[2];
    const float* t      = (const float*)d_in[3];
    const float* w_enc  = (const float*)d_in[4];
    const float* b_enc  = (const float*)d_in[5];
    const float* g_feat = (const float*)d_in[6];
    const float* b_feat = (const float*)d_in[7];
    const float* w_pos  = (const float*)d_in[8];
    const float* b_pos  = (const float*)d_in[9];
    const float* w_neg  = (const float*)d_in[10];
    const float* b_neg  = (const float*)d_in[11];
    const float* w_psi  = (const float*)d_in[12];
    const float* g_ode  = (const float*)d_in[13];
    const float* b_ode  = (const float*)d_in[14];

    const int n = in_sizes[0] / NFEAT;      // 100000
    const int E = in_sizes[1] / 2;          // 1600000

    char* p = (char*)d_ws;
    auto carve = [&](size_t bytes) {
        void* r = (void*)p;
        p += (bytes + 255) & ~(size_t)255;
        return r;
    };
    float*  h       = (float*)carve((size_t)n * HID * 4);
    __half* hnA     = (__half*)carve((size_t)n * HID * 2);
    __half* hnB     = (__half*)carve((size_t)n * HID * 2);
    float*  kacc    = (float*)carve((size_t)n * HID * 4);
    float*  dinvP   = (float*)carve((size_t)n * 4);
    float*  invdegP = (float*)carve((size_t)n * 4);
    float*  dinvN   = (float*)carve((size_t)n * 4);
    float*  invdegN = (float*)carve((size_t)n * 4);
    int*    cntP    = (int*)carve((size_t)n * 4);
    int*    cntN    = (int*)carve((size_t)n * 4);
    int*    rpP     = (int*)carve((size_t)(n + 1) * 4);
    int*    rpN     = (int*)carve((size_t)(n + 1) * 4);
    int*    curP    = (int*)carve((size_t)n * 4);
    int*    curN    = (int*)carve((size_t)n * 4);
    int2*   edP     = (int2*)carve((size_t)E * 8);
    int2*   edN     = (int2*)carve((size_t)E * 8);
    float*  wpp     = (float*)carve((size_t)HID * HID * 4);
    float*  wnn     = (float*)carve((size_t)HID * HID * 4);
    float*  cbias   = (float*)carve((size_t)HID * 4);
    const int nb    = (n + 1023) / 1024;    // 98 blocks per graph (<=256)
    int*    partials= (int*)carve((size_t)(2 * nb) * 4);
    (void)ws_size; (void)n_in; (void)out_size;

    const int* srcP = eip;
    const int* dstP = eip + E;
    const int* srcN = ein;
    const int* dstN = ein + E;

    // --- graph preprocessing (amortized over 32 fused evals) ---
    hipMemsetAsync(cntP, 0, (size_t)n * 4, stream);
    hipMemsetAsync(cntN, 0, (size_t)n * 4, stream);
    hist_kernel<<<2048, 256, 0, stream>>>(dstP, dstN, cntP, cntN, E);
    deg_kernel<<<(n + 255) / 256, 256, 0, stream>>>(cntP, cntN, dinvP, invdegP, dinvN, invdegN, n);
    scanA_kernel<<<2 * nb, 256, 0, stream>>>(cntP, cntN, rpP, rpN, partials, n, nb);
    scanB_kernel<<<2, 256, 0, stream>>>(partials, rpP, rpN, n, nb);
    scanC_kernel<<<2 * nb, 256, 0, stream>>>(rpP, rpN, curP, curN, partials, n, nb);
    fill_kernel<<<2048, 256, 0, stream>>>(srcP, dstP, srcN, dstN, dinvP, dinvN,
                                          curP, curN, edP, edN, E);
    wcomb_kernel<<<1, 1024, 0, stream>>>(w_pos, b_pos, w_neg, b_neg, w_psi, wpp, wnn, cbias);

    // --- encoder: h0 (fp32) and its ode-LN (fp16, into hnA) ---
    encoder_kernel<<<(n + 255) / 256, 256, 0, stream>>>(x, w_enc, b_enc, g_feat, b_feat,
                                                        g_ode, b_ode, h, hnA, n);

    // --- 8 RK4 steps x 4 stages, hn ping-pong ---
    const int fg = (n * HID + 255) / 256;   // 32 lanes per node
    __half* cur = hnA;
    __half* nxt = hnB;
    for (int s = 0; s < 8; ++s) {
        for (int st = 0; st < 4; ++st) {
            bool last = (s == 7 && st == 3);
            if (st == 0)
                fused_kernel<0, false><<<fg, 256, 0, stream>>>(cur, nxt, rpP, edP, invdegP,
                    rpN, edN, invdegN, wpp, wnn, cbias, g_ode, b_ode, t, h, kacc,
                    (float*)d_out, n);
            else if (st == 1)
                fused_kernel<1, false><<<fg, 256, 0, stream>>>(cur, nxt, rpP, edP, invdegP,
                    rpN, edN, invdegN, wpp, wnn, cbias, g_ode, b_ode, t, h, kacc,
                    (float*)d_out, n);
            else if (st == 2)
                fused_kernel<2, false><<<fg, 256, 0, stream>>>(cur, nxt, rpP, edP, invdegP,
                    rpN, edN, invdegN, wpp, wnn, cbias, g_ode, b_ode, t, h, kacc,
                    (float*)d_out, n);
            else if (!last)
                fused_kernel<3, false><<<fg, 256, 0, stream>>>(cur, nxt, rpP, edP, invdegP,
                    rpN, edN, invdegN, wpp, wnn, cbias, g_ode, b_ode, t, h, kacc,
                    (float*)d_out, n);
            else
                fused_kernel<3, true><<<fg, 256, 0, stream>>>(cur, nxt, rpP, edP, invdegP,
                    rpN, edN, invdegN, wpp, wnn, cbias, g_ode, b_ode, t, h, kacc,
                    (float*)d_out, n);
            __half* tmp = cur; cur = nxt; nxt = tmp;
        }
    }
}